// Round 15
// baseline (996.699 us; speedup 1.0000x reference)
//
#include <hip/hip_runtime.h>
#include <math.h>

// BracketNet: ctx_{s+1} = GELU_exact(Wc·ctx_s + (b + Wx·x_s)); out_s = x_s + ctx_{s+1}
// pass1: z = b + Wx·x, parallel, LDS-broadcast GEMV at 8 waves/SIMD (~190 us).
// pass2: serial chain; ONE WAVE RUNS TWO same-head chains (b, b+1) with fully
//        interleaved instruction streams, so chain A's dependency-latency
//        bubbles (r14: ~335 of 535 cyc/step) are filled by chain B's
//        independent ops. f16-pair dot2 GEMV, batched readlanes + fences,
//        counted-vmcnt volatile-asm prefetch (6 vmem/pair-step, depth 4),
//        SGPR-base addressing (SALU increments, voff = lane*4).
//
// r10 pairing failed from readlane->fma ADJACENCY (hazard stalls in both
// chains, serial). r11+ structure is hazard-clean; bubbles are latency-only
// -> fillable by a second in-order stream.

typedef float    f32x4 __attribute__((ext_vector_type(4)));
typedef _Float16 f16x2 __attribute__((ext_vector_type(2)));

#define S_LEN 2048
#define B_SZ  64
#define D_SZ  512
#define DIM   64
#define STRIDE ((size_t)(B_SZ * D_SZ))   // floats between consecutive s

// Branchless exact-GELU (A&S 7.1.26 erf, |eps|<=1.5e-7) — used by pass1 path.
__device__ __forceinline__ float gelu_exact(float y) {
    const float ax = fabsf(y) * 0.70710678118654752440f;
    const float t  = __builtin_amdgcn_rcpf(fmaf(0.3275911f, ax, 1.0f));
    float p = fmaf(1.061405429f, t, -1.453152027f);
    p = fmaf(p, t, 1.421413741f);
    p = fmaf(p, t, -0.284496736f);
    p = fmaf(p, t, 0.254829592f);
    p *= t;
    const float e = __builtin_amdgcn_exp2f(-ax * ax * 1.44269504088896f);
    float er = fmaf(-p, e, 1.0f);
    er = copysignf(er, y);
    return 0.5f * y * (1.0f + er);
}

__device__ __forceinline__ int pkrtz(float a, float b) {
    return __builtin_bit_cast(int, __builtin_amdgcn_cvt_pkrtz(a, b));
}

// ---------------- Pass 1 (unchanged from round 9): LDS-broadcast GEMV.
__device__ __forceinline__ float gemv64(const f32x4* vv, const f32x4 (&w)[16],
                                        float base) {
    float a0 = base, a1 = 0.f, a2 = 0.f, a3 = 0.f;
    float a4 = 0.f, a5 = 0.f, a6 = 0.f, a7 = 0.f;
#pragma unroll
    for (int j = 0; j < 16; j += 2) {
        const f32x4 u0 = vv[j], u1 = vv[j + 1];
        a0 = fmaf(w[j].x,     u0.x, a0);
        a1 = fmaf(w[j].y,     u0.y, a1);
        a2 = fmaf(w[j].z,     u0.z, a2);
        a3 = fmaf(w[j].w,     u0.w, a3);
        a4 = fmaf(w[j + 1].x, u1.x, a4);
        a5 = fmaf(w[j + 1].y, u1.y, a5);
        a6 = fmaf(w[j + 1].z, u1.z, a6);
        a7 = fmaf(w[j + 1].w, u1.w, a7);
    }
    return ((a0 + a1) + (a2 + a3)) + ((a4 + a5) + (a6 + a7));
}

__global__ __launch_bounds__(64, 1) void bracket_pass1(
    const float* __restrict__ src, const float* __restrict__ W,
    const float* __restrict__ bias, float* __restrict__ zout)
{
    const int lane = threadIdx.x;
    const int ck   = blockIdx.x >> 9;          // 0..15 (128 s each)
    const int bb   = (blockIdx.x >> 3) & 63;
    const int hh   = blockIdx.x & 7;

    f32x4 w[16];
    {
        const float* wb = W + (size_t)(hh * DIM + lane) * (2 * DIM) + DIM;
#pragma unroll
        for (int i = 0; i < 16; ++i)
            asm volatile("global_load_dwordx4 %0, %1, off offset:%2"
                         : "=v"(w[i]) : "v"(wb), "i"(16 * i));
    }
    asm volatile("s_waitcnt vmcnt(0)" ::: "memory");
    __builtin_amdgcn_sched_barrier(0);

    const float bv = bias[hh * DIM + lane];

    __shared__ __align__(16) float xsl[2][DIM];   // 512 B ping-pong

    const float* sp = src  + (size_t)(ck * 128) * STRIDE + (size_t)bb * D_SZ + hh * DIM + lane;
    float*       zp = zout + (size_t)(ck * 128) * STRIDE + (size_t)bb * D_SZ + hh * DIM + lane;

    float x0 = sp[0], x1 = sp[STRIDE];
    const float* pp    = sp + 2 * STRIDE;
    const float* plast = sp + 127 * STRIDE;

#define P1STEP(cur, xc)                                                       \
    do {                                                                      \
        xsl[cur][lane] = xc;                                                  \
        const float xn = *pp;                                                 \
        pp = (pp < plast) ? (pp + STRIDE) : plast;                            \
        const float y = gemv64((const f32x4*)xsl[cur], w, bv);                \
        *zp = y;                                                              \
        zp += STRIDE;                                                         \
        xc = xn;                                                              \
    } while (0)

    for (int i = 0; i < 128; i += 2) {
        P1STEP(0, x0);
        P1STEP(1, x1);
    }
#undef P1STEP
}

// ---------------- Pass 2: two same-head chains per wave, interleaved.
__device__ __forceinline__ float fdot2h(int pack, int wpk, float acc) {
#if __has_builtin(__builtin_amdgcn_fdot2)
    return __builtin_amdgcn_fdot2(__builtin_bit_cast(f16x2, pack),
                                  __builtin_bit_cast(f16x2, wpk), acc, false);
#else
    float d;
    asm("v_dot2_f32_f16 %0, %1, %2, %3"
        : "=v"(d)
        : "v"(__builtin_bit_cast(f16x2, pack)),
          "v"(__builtin_bit_cast(f16x2, wpk)), "v"(acc));
    return d;
#endif
}

// SGPR-base vmem: uniform base in SGPR pair, per-lane voff VGPR; volatile ->
// strict program order, cannot sink.
#define GLOADS(dst, base, voff) \
    asm volatile("global_load_dword %0, %1, %2" : "=v"(dst) : "v"(voff), "s"(base))
#define GSTORES(val, base, voff) \
    asm volatile("global_store_dword %1, %0, %2" : : "v"(val), "v"(voff), "s"(base) : "memory")

// Batch m for BOTH chains: 32 readlanes (16 A + 16 B), fence, 32 dot2 A/B
// interleaved. Pair k = 16m+j uses wp[k] (shared: same head).
#define DOT16_2(m)                                                            \
    do {                                                                      \
        const int tA0  = __builtin_amdgcn_readlane(gpiA, 32 * m + 0);         \
        const int tA1  = __builtin_amdgcn_readlane(gpiA, 32 * m + 2);         \
        const int tA2  = __builtin_amdgcn_readlane(gpiA, 32 * m + 4);         \
        const int tA3  = __builtin_amdgcn_readlane(gpiA, 32 * m + 6);         \
        const int tA4  = __builtin_amdgcn_readlane(gpiA, 32 * m + 8);         \
        const int tA5  = __builtin_amdgcn_readlane(gpiA, 32 * m + 10);        \
        const int tA6  = __builtin_amdgcn_readlane(gpiA, 32 * m + 12);        \
        const int tA7  = __builtin_amdgcn_readlane(gpiA, 32 * m + 14);        \
        const int tA8  = __builtin_amdgcn_readlane(gpiA, 32 * m + 16);        \
        const int tA9  = __builtin_amdgcn_readlane(gpiA, 32 * m + 18);        \
        const int tA10 = __builtin_amdgcn_readlane(gpiA, 32 * m + 20);        \
        const int tA11 = __builtin_amdgcn_readlane(gpiA, 32 * m + 22);        \
        const int tA12 = __builtin_amdgcn_readlane(gpiA, 32 * m + 24);        \
        const int tA13 = __builtin_amdgcn_readlane(gpiA, 32 * m + 26);        \
        const int tA14 = __builtin_amdgcn_readlane(gpiA, 32 * m + 28);        \
        const int tA15 = __builtin_amdgcn_readlane(gpiA, 32 * m + 30);        \
        const int tB0  = __builtin_amdgcn_readlane(gpiB, 32 * m + 0);         \
        const int tB1  = __builtin_amdgcn_readlane(gpiB, 32 * m + 2);         \
        const int tB2  = __builtin_amdgcn_readlane(gpiB, 32 * m + 4);         \
        const int tB3  = __builtin_amdgcn_readlane(gpiB, 32 * m + 6);         \
        const int tB4  = __builtin_amdgcn_readlane(gpiB, 32 * m + 8);         \
        const int tB5  = __builtin_amdgcn_readlane(gpiB, 32 * m + 10);        \
        const int tB6  = __builtin_amdgcn_readlane(gpiB, 32 * m + 12);        \
        const int tB7  = __builtin_amdgcn_readlane(gpiB, 32 * m + 14);        \
        const int tB8  = __builtin_amdgcn_readlane(gpiB, 32 * m + 16);        \
        const int tB9  = __builtin_amdgcn_readlane(gpiB, 32 * m + 18);        \
        const int tB10 = __builtin_amdgcn_readlane(gpiB, 32 * m + 20);        \
        const int tB11 = __builtin_amdgcn_readlane(gpiB, 32 * m + 22);        \
        const int tB12 = __builtin_amdgcn_readlane(gpiB, 32 * m + 24);        \
        const int tB13 = __builtin_amdgcn_readlane(gpiB, 32 * m + 26);        \
        const int tB14 = __builtin_amdgcn_readlane(gpiB, 32 * m + 28);        \
        const int tB15 = __builtin_amdgcn_readlane(gpiB, 32 * m + 30);        \
        __builtin_amdgcn_sched_barrier(0);                                    \
        aA0 = fdot2h(tA0,  wp[16 * m + 0],  aA0);                             \
        aB0 = fdot2h(tB0,  wp[16 * m + 0],  aB0);                             \
        aA1 = fdot2h(tA1,  wp[16 * m + 1],  aA1);                             \
        aB1 = fdot2h(tB1,  wp[16 * m + 1],  aB1);                             \
        aA2 = fdot2h(tA2,  wp[16 * m + 2],  aA2);                             \
        aB2 = fdot2h(tB2,  wp[16 * m + 2],  aB2);                             \
        aA3 = fdot2h(tA3,  wp[16 * m + 3],  aA3);                             \
        aB3 = fdot2h(tB3,  wp[16 * m + 3],  aB3);                             \
        aA4 = fdot2h(tA4,  wp[16 * m + 4],  aA4);                             \
        aB4 = fdot2h(tB4,  wp[16 * m + 4],  aB4);                             \
        aA5 = fdot2h(tA5,  wp[16 * m + 5],  aA5);                             \
        aB5 = fdot2h(tB5,  wp[16 * m + 5],  aB5);                             \
        aA6 = fdot2h(tA6,  wp[16 * m + 6],  aA6);                             \
        aB6 = fdot2h(tB6,  wp[16 * m + 6],  aB6);                             \
        aA7 = fdot2h(tA7,  wp[16 * m + 7],  aA7);                             \
        aB7 = fdot2h(tB7,  wp[16 * m + 7],  aB7);                             \
        aA0 = fdot2h(tA8,  wp[16 * m + 8],  aA0);                             \
        aB0 = fdot2h(tB8,  wp[16 * m + 8],  aB0);                             \
        aA1 = fdot2h(tA9,  wp[16 * m + 9],  aA1);                             \
        aB1 = fdot2h(tB9,  wp[16 * m + 9],  aB1);                             \
        aA2 = fdot2h(tA10, wp[16 * m + 10], aA2);                             \
        aB2 = fdot2h(tB10, wp[16 * m + 10], aB2);                             \
        aA3 = fdot2h(tA11, wp[16 * m + 11], aA3);                             \
        aB3 = fdot2h(tB11, wp[16 * m + 11], aB3);                             \
        aA4 = fdot2h(tA12, wp[16 * m + 12], aA4);                             \
        aB4 = fdot2h(tB12, wp[16 * m + 12], aB4);                             \
        aA5 = fdot2h(tA13, wp[16 * m + 13], aA5);                             \
        aB5 = fdot2h(tB13, wp[16 * m + 13], aB5);                             \
        aA6 = fdot2h(tA14, wp[16 * m + 14], aA6);                             \
        aB6 = fdot2h(tB14, wp[16 * m + 14], aB6);                             \
        aA7 = fdot2h(tA15, wp[16 * m + 15], aA7);                             \
        aB7 = fdot2h(tB15, wp[16 * m + 15], aB7);                             \
    } while (0)

__global__ __launch_bounds__(64, 1) void bracket_pass2(
    const float* __restrict__ src, const float* __restrict__ W,
    float* __restrict__ out)   // out holds z on entry; overwritten with result
{
    const int lane = threadIdx.x;
    const int hh   = blockIdx.x & 7;             // head (shared weights)
    const int b0   = (blockIdx.x >> 3) * 2;      // chains (b0,hh), (b0+1,hh)

    // Wc row fp32 (pinned), packed to f16x2 pairs stored as int (shared A/B).
    f32x4 w[16];
    {
        const float* wb = W + (size_t)(hh * DIM + lane) * (2 * DIM);
#pragma unroll
        for (int i = 0; i < 16; ++i)
            asm volatile("global_load_dwordx4 %0, %1, off offset:%2"
                         : "=v"(w[i]) : "v"(wb), "i"(16 * i));
    }
    asm volatile("s_waitcnt vmcnt(0)" ::: "memory");
    __builtin_amdgcn_sched_barrier(0);

    int wp[32];
#pragma unroll
    for (int j = 0; j < 16; ++j) {
        wp[2 * j]     = pkrtz(w[j].x, w[j].y);
        wp[2 * j + 1] = pkrtz(w[j].z, w[j].w);
    }

    // Uniform (SGPR) bases; per-lane byte offset in one VGPR.
    const int voff = lane * 4;
    const float* bxA = src + (size_t)b0 * D_SZ + hh * DIM;        // x loads A
    const float* bxB = bxA + D_SZ;                                // x loads B
    const float* bzA = out + (size_t)b0 * D_SZ + hh * DIM;        // z loads A
    const float* bzB = bzA + D_SZ;                                // z loads B
    float*       boA = out + (size_t)b0 * D_SZ + hh * DIM;        // stores A
    float*       boB = boA + D_SZ;                                // stores B

    float xbA[4], zbA[4], xbB[4], zbB[4];
    float gA = 0.0f, gB = 0.0f;   // ctx_0 = 0

    // Prologue: 16 loads, slot-major, order xA,zA,xB,zB per slot.
#pragma unroll
    for (int i = 0; i < 4; ++i) {
        GLOADS(xbA[i], bxA, voff); bxA += STRIDE;
        GLOADS(zbA[i], bzA, voff); bzA += STRIDE;
        GLOADS(xbB[i], bxB, voff); bxB += STRIDE;
        GLOADS(zbB[i], bzB, voff); bzB += STRIDE;
    }

#define STEP2_CORE(i)                                                         \
    do {                                                                      \
        const int giA  = __float_as_int(gA);                                  \
        const int giB  = __float_as_int(gB);                                  \
        const int gshA = __builtin_amdgcn_mov_dpp(giA, 0x101, 0xf, 0xf, true);\
        const int gshB = __builtin_amdgcn_mov_dpp(giB, 0x101, 0xf, 0xf, true);\
        const int gpiA = pkrtz(gA, __int_as_float(gshA));                     \
        const int gpiB = pkrtz(gB, __int_as_float(gshB));                     \
        float aA0 = zbA[i], aA1 = 0.f, aA2 = 0.f, aA3 = 0.f;                  \
        float aA4 = 0.f, aA5 = 0.f, aA6 = 0.f, aA7 = 0.f;                     \
        float aB0 = zbB[i], aB1 = 0.f, aB2 = 0.f, aB3 = 0.f;                  \
        float aB4 = 0.f, aB5 = 0.f, aB6 = 0.f, aB7 = 0.f;                     \
        DOT16_2(0); DOT16_2(1);                                               \
        const float yA = ((aA0 + aA1) + (aA2 + aA3)) + ((aA4 + aA5) + (aA6 + aA7)); \
        const float yB = ((aB0 + aB1) + (aB2 + aB3)) + ((aB4 + aB5) + (aB6 + aB7)); \
        const float axA = fabsf(yA) * 0.70710678118654752440f;                \
        const float axB = fabsf(yB) * 0.70710678118654752440f;                \
        const float tA = __builtin_amdgcn_rcpf(fmaf(0.3275911f, axA, 1.0f));  \
        const float tB = __builtin_amdgcn_rcpf(fmaf(0.3275911f, axB, 1.0f));  \
        float pA = fmaf(1.061405429f, tA, -1.453152027f);                     \
        float pB = fmaf(1.061405429f, tB, -1.453152027f);                     \
        pA = fmaf(pA, tA, 1.421413741f);  pB = fmaf(pB, tB, 1.421413741f);    \
        pA = fmaf(pA, tA, -0.284496736f); pB = fmaf(pB, tB, -0.284496736f);   \
        pA = fmaf(pA, tA, 0.254829592f);  pB = fmaf(pB, tB, 0.254829592f);    \
        pA *= tA; pB *= tB;                                                   \
        const float eA = __builtin_amdgcn_exp2f(-axA * axA * 1.44269504088896f); \
        const float eB = __builtin_amdgcn_exp2f(-axB * axB * 1.44269504088896f); \
        float erA = fmaf(-pA, eA, 1.0f); float erB = fmaf(-pB, eB, 1.0f);     \
        erA = copysignf(erA, yA); erB = copysignf(erB, yB);                   \
        gA = 0.5f * yA * (1.0f + erA); gB = 0.5f * yB * (1.0f + erB);         \
        const float rA = xbA[i] + gA;                                         \
        const float rB = xbB[i] + gB;                                         \
        GSTORES(rA, boA, voff); boA += STRIDE;                                \
        GSTORES(rB, boB, voff); boB += STRIDE;                                \
    } while (0)

#define STEP2L(i, N)                                                          \
    do {                                                                      \
        asm volatile("s_waitcnt vmcnt(" #N ")");                              \
        __builtin_amdgcn_sched_barrier(0);                                    \
        STEP2_CORE(i);                                                        \
        GLOADS(xbA[i], bxA, voff); bxA += STRIDE;                             \
        GLOADS(zbA[i], bzA, voff); bzA += STRIDE;                             \
        GLOADS(xbB[i], bxB, voff); bxB += STRIDE;                             \
        GLOADS(zbB[i], bzB, voff); bzB += STRIDE;                             \
    } while (0)

#define STEP2E(i, N)                                                          \
    do {                                                                      \
        asm volatile("s_waitcnt vmcnt(" #N ")");                              \
        __builtin_amdgcn_sched_barrier(0);                                    \
        STEP2_CORE(i);                                                        \
    } while (0)

    // vmcnt accounting: 6 vmem/pair-step (2 stores + 4 loads), depth 4.
    // Fill: slot-i loads followed by (3-i)*4 prologue loads + i*6 step ops.
    STEP2L(0, 12); STEP2L(1, 14); STEP2L(2, 16); STEP2L(3, 18);
    // Steady state: slot loads have 3 full steps (18 ops) after them.
    for (int blk = 0; blk < 510; ++blk) {
        STEP2L(0, 18); STEP2L(1, 18); STEP2L(2, 18); STEP2L(3, 18);
    }
    // Drain: no new loads; trailing ops = remaining main steps + epi stores.
    STEP2E(0, 18); STEP2E(1, 14); STEP2E(2, 10); STEP2E(3, 6);

#undef STEP2L
#undef STEP2E
#undef STEP2_CORE
}

extern "C" void kernel_launch(void* const* d_in, const int* in_sizes, int n_in,
                              void* d_out, int out_size, void* d_ws, size_t ws_size,
                              hipStream_t stream) {
    const float* src = (const float*)d_in[0];
    const float* W   = (const float*)d_in[1];
    const float* b   = (const float*)d_in[2];
    float* out       = (float*)d_out;

    hipLaunchKernelGGL(bracket_pass1, dim3(B_SZ * 8 * 16), dim3(64), 0, stream,
                       src, W, b, out);
    hipLaunchKernelGGL(bracket_pass2, dim3(B_SZ * 8 / 2), dim3(64), 0, stream,
                       src, W, out);
}

// Round 16
// 603.939 us; speedup vs baseline: 1.6503x; 1.6503x over previous
//
#include <hip/hip_runtime.h>
#include <math.h>

// BracketNet: ctx_{s+1} = GELU_exact(Wc·ctx_s + (b + Wx·x_s)); out_s = x_s + ctx_{s+1}
// pass1: z = b + Wx·x, parallel, LDS-broadcast GEMV at 8 waves/SIMD (~190 us).
// pass2: serial chain, one wave per (b,h). Single-chain critical path only —
//        r15 proved multi-chain per wave CANNOT cut wall time (wall = S x
//        step-latency of one wave, always).
// This round: (a) depth-8 vmem pipeline -> steady vmcnt(21) so the wait never
// blocks on slow store-acks (depth-4's vmcnt(9) waited on stores 3 steps old);
// (b) single 32-readlane batch + ONE fence (r14's two 16-batches serialized
// batch2's RLs behind batch1's dots); (c) shorter gelu tail: 3-term A&S
// 7.1.25 erf (|eps|<=2.5e-5) + fma combine g = fma(0.5y, er, 0.5y).

typedef float    f32x4 __attribute__((ext_vector_type(4)));
typedef _Float16 f16x2 __attribute__((ext_vector_type(2)));

#define S_LEN 2048
#define B_SZ  64
#define D_SZ  512
#define DIM   64
#define STRIDE ((size_t)(B_SZ * D_SZ))   // floats between consecutive s

__device__ __forceinline__ int pkrtz(float a, float b) {
    return __builtin_bit_cast(int, __builtin_amdgcn_cvt_pkrtz(a, b));
}

// 4-term gelu for pass1 reference path (not used in pass2 loop).
__device__ __forceinline__ float gelu_exact(float y) {
    const float ax = fabsf(y) * 0.70710678118654752440f;
    const float t  = __builtin_amdgcn_rcpf(fmaf(0.3275911f, ax, 1.0f));
    float p = fmaf(1.061405429f, t, -1.453152027f);
    p = fmaf(p, t, 1.421413741f);
    p = fmaf(p, t, -0.284496736f);
    p = fmaf(p, t, 0.254829592f);
    p *= t;
    const float e = __builtin_amdgcn_exp2f(-ax * ax * 1.44269504088896f);
    float er = fmaf(-p, e, 1.0f);
    er = copysignf(er, y);
    return 0.5f * y * (1.0f + er);
}

// ---------------- Pass 1 (unchanged from round 9): LDS-broadcast GEMV.
__device__ __forceinline__ float gemv64(const f32x4* vv, const f32x4 (&w)[16],
                                        float base) {
    float a0 = base, a1 = 0.f, a2 = 0.f, a3 = 0.f;
    float a4 = 0.f, a5 = 0.f, a6 = 0.f, a7 = 0.f;
#pragma unroll
    for (int j = 0; j < 16; j += 2) {
        const f32x4 u0 = vv[j], u1 = vv[j + 1];
        a0 = fmaf(w[j].x,     u0.x, a0);
        a1 = fmaf(w[j].y,     u0.y, a1);
        a2 = fmaf(w[j].z,     u0.z, a2);
        a3 = fmaf(w[j].w,     u0.w, a3);
        a4 = fmaf(w[j + 1].x, u1.x, a4);
        a5 = fmaf(w[j + 1].y, u1.y, a5);
        a6 = fmaf(w[j + 1].z, u1.z, a6);
        a7 = fmaf(w[j + 1].w, u1.w, a7);
    }
    return ((a0 + a1) + (a2 + a3)) + ((a4 + a5) + (a6 + a7));
}

__global__ __launch_bounds__(64, 1) void bracket_pass1(
    const float* __restrict__ src, const float* __restrict__ W,
    const float* __restrict__ bias, float* __restrict__ zout)
{
    const int lane = threadIdx.x;
    const int ck   = blockIdx.x >> 9;          // 0..15 (128 s each)
    const int bb   = (blockIdx.x >> 3) & 63;
    const int hh   = blockIdx.x & 7;

    f32x4 w[16];
    {
        const float* wb = W + (size_t)(hh * DIM + lane) * (2 * DIM) + DIM;
#pragma unroll
        for (int i = 0; i < 16; ++i)
            asm volatile("global_load_dwordx4 %0, %1, off offset:%2"
                         : "=v"(w[i]) : "v"(wb), "i"(16 * i));
    }
    asm volatile("s_waitcnt vmcnt(0)" ::: "memory");
    __builtin_amdgcn_sched_barrier(0);

    const float bv = bias[hh * DIM + lane];

    __shared__ __align__(16) float xsl[2][DIM];   // 512 B ping-pong

    const float* sp = src  + (size_t)(ck * 128) * STRIDE + (size_t)bb * D_SZ + hh * DIM + lane;
    float*       zp = zout + (size_t)(ck * 128) * STRIDE + (size_t)bb * D_SZ + hh * DIM + lane;

    float x0 = sp[0], x1 = sp[STRIDE];
    const float* pp    = sp + 2 * STRIDE;
    const float* plast = sp + 127 * STRIDE;

#define P1STEP(cur, xc)                                                       \
    do {                                                                      \
        xsl[cur][lane] = xc;                                                  \
        const float xn = *pp;                                                 \
        pp = (pp < plast) ? (pp + STRIDE) : plast;                            \
        const float y = gemv64((const f32x4*)xsl[cur], w, bv);                \
        *zp = y;                                                              \
        zp += STRIDE;                                                         \
        xc = xn;                                                              \
    } while (0)

    for (int i = 0; i < 128; i += 2) {
        P1STEP(0, x0);
        P1STEP(1, x1);
    }
#undef P1STEP
}

// ---------------- Pass 2: serial chain, single 32-RL batch dot2 GEMV,
// depth-8 counted-vmcnt volatile-asm prefetch.
__device__ __forceinline__ float fdot2h(int pack, int wpk, float acc) {
#if __has_builtin(__builtin_amdgcn_fdot2)
    return __builtin_amdgcn_fdot2(__builtin_bit_cast(f16x2, pack),
                                  __builtin_bit_cast(f16x2, wpk), acc, false);
#else
    float d;
    asm("v_dot2_f32_f16 %0, %1, %2, %3"
        : "=v"(d)
        : "v"(__builtin_bit_cast(f16x2, pack)),
          "v"(__builtin_bit_cast(f16x2, wpk)), "v"(acc));
    return d;
#endif
}

#define GLOAD(dst, ptr) \
    asm volatile("global_load_dword %0, %1, off" : "=v"(dst) : "v"(ptr))
#define GSTORE(val, ptr) \
    asm volatile("global_store_dword %1, %0, off" : : "v"(val), "v"(ptr) : "memory")

// All 32 readlanes (covering k=0..63 as f16 pairs from even lanes), ONE
// fence, then 32 dot2s; dot k -> acc k&7 (8 interleaved chains).
#define DOT32()                                                               \
    do {                                                                      \
        const int t0  = __builtin_amdgcn_readlane(gpi, 0);                    \
        const int t1  = __builtin_amdgcn_readlane(gpi, 2);                    \
        const int t2  = __builtin_amdgcn_readlane(gpi, 4);                    \
        const int t3  = __builtin_amdgcn_readlane(gpi, 6);                    \
        const int t4  = __builtin_amdgcn_readlane(gpi, 8);                    \
        const int t5  = __builtin_amdgcn_readlane(gpi, 10);                   \
        const int t6  = __builtin_amdgcn_readlane(gpi, 12);                   \
        const int t7  = __builtin_amdgcn_readlane(gpi, 14);                   \
        const int t8  = __builtin_amdgcn_readlane(gpi, 16);                   \
        const int t9  = __builtin_amdgcn_readlane(gpi, 18);                   \
        const int t10 = __builtin_amdgcn_readlane(gpi, 20);                   \
        const int t11 = __builtin_amdgcn_readlane(gpi, 22);                   \
        const int t12 = __builtin_amdgcn_readlane(gpi, 24);                   \
        const int t13 = __builtin_amdgcn_readlane(gpi, 26);                   \
        const int t14 = __builtin_amdgcn_readlane(gpi, 28);                   \
        const int t15 = __builtin_amdgcn_readlane(gpi, 30);                   \
        const int t16 = __builtin_amdgcn_readlane(gpi, 32);                   \
        const int t17 = __builtin_amdgcn_readlane(gpi, 34);                   \
        const int t18 = __builtin_amdgcn_readlane(gpi, 36);                   \
        const int t19 = __builtin_amdgcn_readlane(gpi, 38);                   \
        const int t20 = __builtin_amdgcn_readlane(gpi, 40);                   \
        const int t21 = __builtin_amdgcn_readlane(gpi, 42);                   \
        const int t22 = __builtin_amdgcn_readlane(gpi, 44);                   \
        const int t23 = __builtin_amdgcn_readlane(gpi, 46);                   \
        const int t24 = __builtin_amdgcn_readlane(gpi, 48);                   \
        const int t25 = __builtin_amdgcn_readlane(gpi, 50);                   \
        const int t26 = __builtin_amdgcn_readlane(gpi, 52);                   \
        const int t27 = __builtin_amdgcn_readlane(gpi, 54);                   \
        const int t28 = __builtin_amdgcn_readlane(gpi, 56);                   \
        const int t29 = __builtin_amdgcn_readlane(gpi, 58);                   \
        const int t30 = __builtin_amdgcn_readlane(gpi, 60);                   \
        const int t31 = __builtin_amdgcn_readlane(gpi, 62);                   \
        __builtin_amdgcn_sched_barrier(0);                                    \
        a0 = fdot2h(t0,  wp[0],  a0);  a1 = fdot2h(t1,  wp[1],  a1);          \
        a2 = fdot2h(t2,  wp[2],  a2);  a3 = fdot2h(t3,  wp[3],  a3);          \
        a4 = fdot2h(t4,  wp[4],  a4);  a5 = fdot2h(t5,  wp[5],  a5);          \
        a6 = fdot2h(t6,  wp[6],  a6);  a7 = fdot2h(t7,  wp[7],  a7);          \
        a0 = fdot2h(t8,  wp[8],  a0);  a1 = fdot2h(t9,  wp[9],  a1);          \
        a2 = fdot2h(t10, wp[10], a2);  a3 = fdot2h(t11, wp[11], a3);          \
        a4 = fdot2h(t12, wp[12], a4);  a5 = fdot2h(t13, wp[13], a5);          \
        a6 = fdot2h(t14, wp[14], a6);  a7 = fdot2h(t15, wp[15], a7);          \
        a0 = fdot2h(t16, wp[16], a0);  a1 = fdot2h(t17, wp[17], a1);          \
        a2 = fdot2h(t18, wp[18], a2);  a3 = fdot2h(t19, wp[19], a3);          \
        a4 = fdot2h(t20, wp[20], a4);  a5 = fdot2h(t21, wp[21], a5);          \
        a6 = fdot2h(t22, wp[22], a6);  a7 = fdot2h(t23, wp[23], a7);          \
        a0 = fdot2h(t24, wp[24], a0);  a1 = fdot2h(t25, wp[25], a1);          \
        a2 = fdot2h(t26, wp[26], a2);  a3 = fdot2h(t27, wp[27], a3);          \
        a4 = fdot2h(t28, wp[28], a4);  a5 = fdot2h(t29, wp[29], a5);          \
        a6 = fdot2h(t30, wp[30], a6);  a7 = fdot2h(t31, wp[31], a7);          \
    } while (0)

__global__ __launch_bounds__(64, 1) void bracket_pass2(
    const float* __restrict__ src, const float* __restrict__ W,
    float* __restrict__ out)   // out holds z on entry; overwritten with result
{
    const int lane = threadIdx.x;
    const int bb   = blockIdx.x >> 3;
    const int hh   = blockIdx.x & 7;

    // Wc row fp32 (pinned), packed to f16x2 pairs stored as int.
    f32x4 w[16];
    {
        const float* wb = W + (size_t)(hh * DIM + lane) * (2 * DIM);
#pragma unroll
        for (int i = 0; i < 16; ++i)
            asm volatile("global_load_dwordx4 %0, %1, off offset:%2"
                         : "=v"(w[i]) : "v"(wb), "i"(16 * i));
    }
    asm volatile("s_waitcnt vmcnt(0)" ::: "memory");
    __builtin_amdgcn_sched_barrier(0);

    int wp[32];
#pragma unroll
    for (int j = 0; j < 16; ++j) {
        wp[2 * j]     = pkrtz(w[j].x, w[j].y);
        wp[2 * j + 1] = pkrtz(w[j].z, w[j].w);
    }

    const float* sp = src + (size_t)bb * D_SZ + hh * DIM + lane;
    float*       op = out + (size_t)bb * D_SZ + hh * DIM + lane;  // store ptr
    const float* px = sp;                                         // x load ptr
    const float* pz = op;                                         // z load ptr

    float xb[8], zb[8];
    float g = 0.0f;   // ctx_0 = 0

    // Prologue: 16 loads, per-slot order x_i, z_i.
#pragma unroll
    for (int i = 0; i < 8; ++i) {
        GLOAD(xb[i], px); px += STRIDE;
        GLOAD(zb[i], pz); pz += STRIDE;
    }

    // Gelu: 3-term A&S 7.1.25 erf, parallel rcp/exp chains, fma combine.
#define STEP_CORE(i)                                                          \
    do {                                                                      \
        const float zi = zb[i];                                               \
        const int gi  = __float_as_int(g);                                    \
        const int gsh = __builtin_amdgcn_mov_dpp(gi, 0x101, 0xf, 0xf, true);  \
        const int gpi = pkrtz(g, __int_as_float(gsh));                        \
        float a0 = zi, a1 = 0.f, a2 = 0.f, a3 = 0.f;                          \
        float a4 = 0.f, a5 = 0.f, a6 = 0.f, a7 = 0.f;                         \
        DOT32();                                                              \
        const float y = ((a0 + a1) + (a2 + a3)) + ((a4 + a5) + (a6 + a7));    \
        const float ax = fabsf(y) * 0.70710678118654752440f;                  \
        const float t  = __builtin_amdgcn_rcpf(fmaf(0.47047f, ax, 1.0f));     \
        const float e  = __builtin_amdgcn_exp2f(-ax * ax * 1.44269504088896f);\
        float p = fmaf(0.7478556f, t, -0.0958798f);                           \
        p = fmaf(p, t, 0.3480242f);                                           \
        p *= t;                                                               \
        float er = fmaf(-p, e, 1.0f);                                         \
        er = copysignf(er, y);                                                \
        const float m = 0.5f * y;                                             \
        g = fmaf(m, er, m);                                                   \
        const float r = xb[i] + g;                                            \
        GSTORE(r, op);                                                        \
        op += STRIDE;                                                         \
    } while (0)

#define STEPL(i, N)                                                           \
    do {                                                                      \
        asm volatile("s_waitcnt vmcnt(" #N ")");                              \
        __builtin_amdgcn_sched_barrier(0);                                    \
        STEP_CORE(i);                                                         \
        GLOAD(xb[i], px); px += STRIDE;                                       \
        GLOAD(zb[i], pz); pz += STRIDE;                                       \
    } while (0)

#define STEPE(i, N)                                                           \
    do {                                                                      \
        asm volatile("s_waitcnt vmcnt(" #N ")");                              \
        __builtin_amdgcn_sched_barrier(0);                                    \
        STEP_CORE(i);                                                         \
    } while (0)

    // vmcnt accounting, 3 vmem/step (store, load x, load z), depth 8:
    // fill steps 0..7: slot-i loads trailed by 2*(7-i) prologue + 3*i step ops.
    STEPL(0, 14); STEPL(1, 15); STEPL(2, 16); STEPL(3, 17);
    STEPL(4, 18); STEPL(5, 19); STEPL(6, 20); STEPL(7, 21);
    // steady state: slot loads trailed by 7 full steps = 21 ops.
    for (int blk = 0; blk < 254; ++blk) {
        STEPL(0, 21); STEPL(1, 21); STEPL(2, 21); STEPL(3, 21);
        STEPL(4, 21); STEPL(5, 21); STEPL(6, 21); STEPL(7, 21);
    }
    // drain steps 2040..2047: N = 3*(7-i) + i = 21 - 2i.
    STEPE(0, 21); STEPE(1, 19); STEPE(2, 17); STEPE(3, 15);
    STEPE(4, 13); STEPE(5, 11); STEPE(6, 9);  STEPE(7, 7);

#undef STEPL
#undef STEPE
#undef STEP_CORE
}

extern "C" void kernel_launch(void* const* d_in, const int* in_sizes, int n_in,
                              void* d_out, int out_size, void* d_ws, size_t ws_size,
                              hipStream_t stream) {
    const float* src = (const float*)d_in[0];
    const float* W   = (const float*)d_in[1];
    const float* b   = (const float*)d_in[2];
    float* out       = (float*)d_out;

    hipLaunchKernelGGL(bracket_pass1, dim3(B_SZ * 8 * 16), dim3(64), 0, stream,
                       src, W, b, out);
    hipLaunchKernelGGL(bracket_pass2, dim3(B_SZ * 8), dim3(64), 0, stream,
                       src, W, out);
}